// Round 1
// baseline (173.419 us; speedup 1.0000x reference)
//
#include <hip/hip_runtime.h>
#include <math.h>

// NoisyTopKGating: B=4, S=4096, D=2048, E=64, K=2
#define B_ 4
#define S_ 4096
#define D_ 2048
#define E_ 64
#define T_ (B_ * S_)       // 16384 tokens

// GEMM tile config
#define BM 64              // tokens per block
#define BK 32              // k-chunk
#define BN 128             // 64 gate cols + 64 noise cols
#define XS_STRIDE 68       // BM + 4 pad (keeps 16B alignment for b128 reads)
#define WS_STRIDE 132      // BN + 4 pad
#define CT_STRIDE 132

__launch_bounds__(256)
__global__ void noisy_topk_gating_kernel(const float* __restrict__ x,
                                         const float* __restrict__ Wg,
                                         const float* __restrict__ bg,
                                         const float* __restrict__ Wn,
                                         const float* __restrict__ bn,
                                         const float* __restrict__ noise,
                                         float* __restrict__ out_probs,
                                         float* __restrict__ out_idx) {
    // smem reused: staging (Xs 32x68 + Ws 32x132 = 6400 floats) then C tile (64x132 = 8448 floats)
    __shared__ float smem[BM * CT_STRIDE];
    float* Xs = smem;                      // [BK][XS_STRIDE]
    float* Ws = smem + BK * XS_STRIDE;     // [BK][WS_STRIDE]

    const int tid = threadIdx.x;
    const int block_m0 = blockIdx.x * BM;

    // register tile: 8 tokens (m) x 4 cols (n)
    const int n0 = (tid & 31) * 4;         // 32 thread-cols * 4 = 128
    const int m0 = (tid >> 5) * 8;         // 8 thread-rows * 8 = 64

    float acc[8][4];
#pragma unroll
    for (int i = 0; i < 8; ++i)
#pragma unroll
        for (int j = 0; j < 4; ++j) acc[i][j] = 0.f;

    const int sj = tid & 7;    // float4 chunk within 32-wide k slab
    const int sr = tid >> 3;   // 0..31 row group

    for (int k0 = 0; k0 < D_; k0 += BK) {
        __syncthreads();  // protect smem against previous iteration's readers
        // stage x tile: 64 rows x 32 k (transposed into Xs[k][m])
#pragma unroll
        for (int it = 0; it < 2; ++it) {
            const int m = sr + it * 32;
            const float4 v = *reinterpret_cast<const float4*>(
                &x[(size_t)(block_m0 + m) * D_ + k0 + 4 * sj]);
            Xs[(4 * sj + 0) * XS_STRIDE + m] = v.x;
            Xs[(4 * sj + 1) * XS_STRIDE + m] = v.y;
            Xs[(4 * sj + 2) * XS_STRIDE + m] = v.z;
            Xs[(4 * sj + 3) * XS_STRIDE + m] = v.w;
        }
        // stage W tile: 128 rows (64 Wg then 64 Wn) x 32 k (transposed into Ws[k][n])
#pragma unroll
        for (int it = 0; it < 4; ++it) {
            const int n = sr + it * 32;
            const float* wrow = (n < 64) ? &Wg[(size_t)n * D_] : &Wn[(size_t)(n - 64) * D_];
            const float4 v = *reinterpret_cast<const float4*>(&wrow[k0 + 4 * sj]);
            Ws[(4 * sj + 0) * WS_STRIDE + n] = v.x;
            Ws[(4 * sj + 1) * WS_STRIDE + n] = v.y;
            Ws[(4 * sj + 2) * WS_STRIDE + n] = v.z;
            Ws[(4 * sj + 3) * WS_STRIDE + n] = v.w;
        }
        __syncthreads();
#pragma unroll
        for (int k = 0; k < BK; ++k) {
            const float4 a0 = *reinterpret_cast<const float4*>(&Xs[k * XS_STRIDE + m0]);
            const float4 a1 = *reinterpret_cast<const float4*>(&Xs[k * XS_STRIDE + m0 + 4]);
            const float4 b4 = *reinterpret_cast<const float4*>(&Ws[k * WS_STRIDE + n0]);
            const float am[8] = {a0.x, a0.y, a0.z, a0.w, a1.x, a1.y, a1.z, a1.w};
            const float bb[4] = {b4.x, b4.y, b4.z, b4.w};
#pragma unroll
            for (int i = 0; i < 8; ++i)
#pragma unroll
                for (int j = 0; j < 4; ++j)
                    acc[i][j] = fmaf(am[i], bb[j], acc[i][j]);
        }
    }

    // write acc tile to LDS for the per-token epilogue
    __syncthreads();
    float* Ct = smem;  // [BM][CT_STRIDE]
#pragma unroll
    for (int i = 0; i < 8; ++i)
#pragma unroll
        for (int j = 0; j < 4; ++j)
            Ct[(m0 + i) * CT_STRIDE + n0 + j] = acc[i][j];
    __syncthreads();

    // epilogue: 4 waves, 16 tokens each; lane = expert
    const int wave = tid >> 6;
    const int lane = tid & 63;
    const float my_bg = bg[lane];
    const float my_bn = bn[lane];
#pragma unroll 1
    for (int tt = 0; tt < 16; ++tt) {
        const int tl = wave * 16 + tt;
        const size_t tg = (size_t)block_m0 + tl;
        const float g = Ct[tl * CT_STRIDE + lane] + my_bg;
        const float nl = Ct[tl * CT_STRIDE + 64 + lane] + my_bn;
        // softplus(z) = max(z,0) + log1p(exp(-|z|))   (jax logaddexp form)
        const float sp = fmaxf(nl, 0.f) + log1pf(expf(-fabsf(nl)));
        const float nz = noise[tg * E_ + lane];
        const float noisy = g + nz * sp;

        // top-1: lexicographic max on (value, -index)
        float v = noisy;
        int idx = lane;
#pragma unroll
        for (int off = 32; off > 0; off >>= 1) {
            const float ov = __shfl_xor(v, off);
            const int oi = __shfl_xor(idx, off);
            if (ov > v || (ov == v && oi < idx)) { v = ov; idx = oi; }
        }
        const float v1 = v;
        const int i1 = idx;
        // top-2
        v = (lane == i1) ? -INFINITY : noisy;
        idx = lane;
#pragma unroll
        for (int off = 32; off > 0; off >>= 1) {
            const float ov = __shfl_xor(v, off);
            const int oi = __shfl_xor(idx, off);
            if (ov > v || (ov == v && oi < idx)) { v = ov; idx = oi; }
        }
        const float v2 = v;
        const int i2 = idx;

        // softmax over {v1, v2} with -inf elsewhere
        const float e2 = expf(v2 - v1);
        const float denom = 1.f + e2;
        const float p = (lane == i1) ? (1.f / denom)
                                     : ((lane == i2) ? (e2 / denom) : 0.f);
        out_probs[tg * E_ + lane] = p;
        if (lane == 0) {
            out_idx[tg * 2 + 0] = (float)i1;
            out_idx[tg * 2 + 1] = (float)i2;
        }
    }
}

extern "C" void kernel_launch(void* const* d_in, const int* in_sizes, int n_in,
                              void* d_out, int out_size, void* d_ws, size_t ws_size,
                              hipStream_t stream) {
    const float* x = (const float*)d_in[0];
    const float* Wg = (const float*)d_in[1];
    const float* bg = (const float*)d_in[2];
    const float* Wn = (const float*)d_in[3];
    const float* bn = (const float*)d_in[4];
    const float* noise = (const float*)d_in[5];
    float* out_probs = (float*)d_out;
    float* out_idx = out_probs + (size_t)T_ * E_;

    dim3 grid(T_ / BM);
    dim3 block(256);
    hipLaunchKernelGGL(noisy_topk_gating_kernel, grid, block, 0, stream,
                       x, Wg, bg, Wn, bn, noise, out_probs, out_idx);
}

// Round 4
// 87.051 us; speedup vs baseline: 1.9922x; 1.9922x over previous
//
#include <hip/hip_runtime.h>
#include <math.h>
#include <stdint.h>

// NoisyTopKGating: B=4, S=4096, D=2048, E=64, K=2
#define D_ 2048
#define E_ 64
#define T_ 16384

#define BM 32
#define BK 64
#define KTILES (D_ / BK)      // 32
#define ROWB 144              // LDS row stride bytes (72 bf16: 64 data + 8 pad)
#define PLANE_B (32 * ROWB)   // 4608 B per bf16 plane
#define CT_STRIDE 132         // fp32 C tile stride (epilogue)

typedef __attribute__((ext_vector_type(8))) short s8v;   // 8 bf16 (4 VGPR)
typedef __attribute__((ext_vector_type(4))) float f4v;   // MFMA acc

__device__ __forceinline__ unsigned short bf16_rne(float f) {
    union { float f; uint32_t u; } c; c.f = f;
    return (unsigned short)((c.u + 0x7FFFu + ((c.u >> 16) & 1u)) >> 16);
}
__device__ __forceinline__ float bf16_tof(unsigned short b) {
    union { uint32_t u; float f; } c; c.u = ((uint32_t)b) << 16;
    return c.f;
}

// ================= per-token noisy top-2 epilogue (shared) ==================
__device__ __forceinline__ void topk_epilogue(float g, float nl, float nz,
                                              int lane, size_t tg,
                                              float* __restrict__ out_probs,
                                              float* __restrict__ out_idx) {
    // softplus(z) = max(z,0) + log1p(exp(-|z|))
    const float sp = fmaxf(nl, 0.f) + log1pf(expf(-fabsf(nl)));
    const float noisy = g + nz * sp;

    float v = noisy;
    int idx = lane;
#pragma unroll
    for (int off = 32; off > 0; off >>= 1) {
        const float ov = __shfl_xor(v, off);
        const int oi = __shfl_xor(idx, off);
        if (ov > v || (ov == v && oi < idx)) { v = ov; idx = oi; }
    }
    const float v1 = v;
    const int i1 = idx;
    v = (lane == i1) ? -INFINITY : noisy;
    idx = lane;
#pragma unroll
    for (int off = 32; off > 0; off >>= 1) {
        const float ov = __shfl_xor(v, off);
        const int oi = __shfl_xor(idx, off);
        if (ov > v || (ov == v && oi < idx)) { v = ov; idx = oi; }
    }
    const float v2 = v;
    const int i2 = idx;

    const float e2 = expf(v2 - v1);
    const float denom = 1.f + e2;
    const float p = (lane == i1) ? (1.f / denom)
                                 : ((lane == i2) ? (e2 / denom) : 0.f);
    out_probs[tg * E_ + lane] = p;
    if (lane == 0) {
        out_idx[tg * 2 + 0] = (float)i1;
        out_idx[tg * 2 + 1] = (float)i2;
    }
}

// ---------------- kernel 1: pre-split W = [Wg;Wn] into 3 bf16 planes --------
// Frag-linear layout: plane p, n-frag f(8), k-step s(64), lane(64) -> 8 bf16.
// b-frag semantics: n = f*16 + (lane&15), k = s*32 + (lane>>4)*8 + i.
__global__ void w_split_kernel(const float* __restrict__ Wg,
                               const float* __restrict__ Wn,
                               unsigned short* __restrict__ wsp) {
    const int idx = blockIdx.x * blockDim.x + threadIdx.x;  // 0..32767
    const int lane = idx & 63;
    const int s = (idx >> 6) & 63;
    const int f = idx >> 12;
    const int n = f * 16 + (lane & 15);
    const int k0 = s * 32 + ((lane >> 4) << 3);
    const float* src = (n < 64) ? &Wg[(size_t)n * D_ + k0]
                                : &Wn[(size_t)(n - 64) * D_ + k0];
    s8v hv, mv, lv;
#pragma unroll
    for (int i = 0; i < 8; ++i) {
        const float f0 = src[i];
        const unsigned short hb = bf16_rne(f0);
        const float r1 = f0 - bf16_tof(hb);
        const unsigned short mb = bf16_rne(r1);
        const unsigned short lb = bf16_rne(r1 - bf16_tof(mb));
        hv[i] = (short)hb; mv[i] = (short)mb; lv[i] = (short)lb;
    }
    s8v* out = (s8v*)wsp;
    const int PLANE_FRAGS = 8 * 64 * 64;  // 32768 frags of 16 B per plane
    out[0 * PLANE_FRAGS + idx] = hv;
    out[1 * PLANE_FRAGS + idx] = mv;
    out[2 * PLANE_FRAGS + idx] = lv;
}

// ---------------- kernel 2: fused split-bf16 MFMA GEMM + noisy top-2 --------
__launch_bounds__(256)
__global__ void gemm_topk_kernel(const float* __restrict__ x,
                                 const unsigned short* __restrict__ wsp,
                                 const float* __restrict__ bg,
                                 const float* __restrict__ bn,
                                 const float* __restrict__ noise,
                                 float* __restrict__ out_probs,
                                 float* __restrict__ out_idx) {
    __shared__ __align__(16) char smem[BM * CT_STRIDE * 4];  // 16896 B
    const int tid = threadIdx.x;
    const int lane = tid & 63;
    const int wv = tid >> 6;           // wave id = n-quadrant (32 cols each)
    const int block_m0 = blockIdx.x * BM;

    // staging: thread -> token row sr (0..31), k-chunk sc (8 floats)
    const int sr = tid >> 3;
    const int sc = tid & 7;
    const int wbyte = sr * ROWB + sc * 16;

    // A-frag addressing: row = lane&15 (+16*mi), k = (lane>>4)*8 + i (+32*ss)
    const int arow = lane & 15;
    const int abase = arow * ROWB + (lane >> 4) * 16;

    const s8v* wsv = (const s8v*)wsp;
    const int fb = wv * 2;  // this wave's first n-frag

    f4v acc00{}, acc01{}, acc10{}, acc11{};  // [mi][ni]

    const float* xrow = &x[(size_t)(block_m0 + sr) * D_ + sc * 8];

    for (int t = 0; t < KTILES; ++t) {
        __syncthreads();
        // ---- stage x tile: load 8 fp32, triple-split, write 3 LDS planes
        const float4 v0 = *(const float4*)(xrow + t * BK);
        const float4 v1 = *(const float4*)(xrow + t * BK + 4);
        const float xf[8] = {v0.x, v0.y, v0.z, v0.w, v1.x, v1.y, v1.z, v1.w};
        s8v hv, mv, lv;
#pragma unroll
        for (int i = 0; i < 8; ++i) {
            const float f0 = xf[i];
            const unsigned short hb = bf16_rne(f0);
            const float r1 = f0 - bf16_tof(hb);
            const unsigned short mb = bf16_rne(r1);
            const unsigned short lb = bf16_rne(r1 - bf16_tof(mb));
            hv[i] = (short)hb; mv[i] = (short)mb; lv[i] = (short)lb;
        }
        *(s8v*)(smem + 0 * PLANE_B + wbyte) = hv;
        *(s8v*)(smem + 1 * PLANE_B + wbyte) = mv;
        *(s8v*)(smem + 2 * PLANE_B + wbyte) = lv;
        __syncthreads();

#pragma unroll
        for (int ss = 0; ss < 2; ++ss) {
            const size_t bbase = (size_t)(t * 2 + ss) * 64 + lane;
            // B frags (global, L2-resident, coalesced)
            const s8v b0n0 = wsv[(size_t)(0 * 8 + fb + 0) * 4096 + bbase];
            const s8v b0n1 = wsv[(size_t)(0 * 8 + fb + 1) * 4096 + bbase];
            const s8v b1n0 = wsv[(size_t)(1 * 8 + fb + 0) * 4096 + bbase];
            const s8v b1n1 = wsv[(size_t)(1 * 8 + fb + 1) * 4096 + bbase];
            const s8v b2n0 = wsv[(size_t)(2 * 8 + fb + 0) * 4096 + bbase];
            const s8v b2n1 = wsv[(size_t)(2 * 8 + fb + 1) * 4096 + bbase];
            // A frags (LDS)
            const int ab = ss * 64 + abase;
            const s8v a0m0 = *(const s8v*)(smem + 0 * PLANE_B + 0 * 2304 + ab);
            const s8v a0m1 = *(const s8v*)(smem + 0 * PLANE_B + 1 * 2304 + ab);
            const s8v a1m0 = *(const s8v*)(smem + 1 * PLANE_B + 0 * 2304 + ab);
            const s8v a1m1 = *(const s8v*)(smem + 1 * PLANE_B + 1 * 2304 + ab);
            const s8v a2m0 = *(const s8v*)(smem + 2 * PLANE_B + 0 * 2304 + ab);
            const s8v a2m1 = *(const s8v*)(smem + 2 * PLANE_B + 1 * 2304 + ab);

#define MFMA_(A, Bf, C) C = __builtin_amdgcn_mfma_f32_16x16x32_bf16(A, Bf, C, 0, 0, 0)
            // hi*hi
            MFMA_(a0m0, b0n0, acc00); MFMA_(a0m0, b0n1, acc01);
            MFMA_(a0m1, b0n0, acc10); MFMA_(a0m1, b0n1, acc11);
            // hi*mid
            MFMA_(a0m0, b1n0, acc00); MFMA_(a0m0, b1n1, acc01);
            MFMA_(a0m1, b1n0, acc10); MFMA_(a0m1, b1n1, acc11);
            // mid*hi
            MFMA_(a1m0, b0n0, acc00); MFMA_(a1m0, b0n1, acc01);
            MFMA_(a1m1, b0n0, acc10); MFMA_(a1m1, b0n1, acc11);
            // hi*lo
            MFMA_(a0m0, b2n0, acc00); MFMA_(a0m0, b2n1, acc01);
            MFMA_(a0m1, b2n0, acc10); MFMA_(a0m1, b2n1, acc11);
            // mid*mid
            MFMA_(a1m0, b1n0, acc00); MFMA_(a1m0, b1n1, acc01);
            MFMA_(a1m1, b1n0, acc10); MFMA_(a1m1, b1n1, acc11);
            // lo*hi
            MFMA_(a2m0, b0n0, acc00); MFMA_(a2m0, b0n1, acc01);
            MFMA_(a2m1, b0n0, acc10); MFMA_(a2m1, b0n1, acc11);
#undef MFMA_
        }
    }

    // ---- epilogue: C tile to LDS (fp32), then per-token noisy top-2
    __syncthreads();
    float* Ct = (float*)smem;  // [32][CT_STRIDE]
    {
        const int ko4 = (lane >> 4) * 4;
        const f4v* accs[2][2] = {{&acc00, &acc01}, {&acc10, &acc11}};
#pragma unroll
        for (int mi = 0; mi < 2; ++mi)
#pragma unroll
            for (int ni = 0; ni < 2; ++ni) {
                const int col = wv * 32 + ni * 16 + arow;
#pragma unroll
                for (int r = 0; r < 4; ++r) {
                    const int row = mi * 16 + ko4 + r;
                    Ct[row * CT_STRIDE + col] = (*accs[mi][ni])[r];
                }
            }
    }
    __syncthreads();

    const float my_bg = bg[lane];
    const float my_bn = bn[lane];
#pragma unroll 1
    for (int tt = 0; tt < 8; ++tt) {
        const int tl = wv * 8 + tt;
        const size_t tg = (size_t)block_m0 + tl;
        const float g = Ct[tl * CT_STRIDE + lane] + my_bg;
        const float nl = Ct[tl * CT_STRIDE + 64 + lane] + my_bn;
        const float nz = noise[tg * E_ + lane];
        topk_epilogue(g, nl, nz, lane, tg, out_probs, out_idx);
    }
}

// ---------------- fallback: round-1 pure-f32 fused kernel (no ws) ----------
#define FBM 64
#define FBK 32
#define XS_STRIDE 68
#define WS_STRIDE 132
#define FCT_STRIDE 132

__launch_bounds__(256)
__global__ void noisy_topk_f32_kernel(const float* __restrict__ x,
                                      const float* __restrict__ Wg,
                                      const float* __restrict__ bg,
                                      const float* __restrict__ Wn,
                                      const float* __restrict__ bn,
                                      const float* __restrict__ noise,
                                      float* __restrict__ out_probs,
                                      float* __restrict__ out_idx) {
    __shared__ float smem[FBM * FCT_STRIDE];
    float* Xs = smem;
    float* Ws = smem + FBK * XS_STRIDE;

    const int tid = threadIdx.x;
    const int block_m0 = blockIdx.x * FBM;
    const int n0 = (tid & 31) * 4;
    const int m0 = (tid >> 5) * 8;

    float acc[8][4];
#pragma unroll
    for (int i = 0; i < 8; ++i)
#pragma unroll
        for (int j = 0; j < 4; ++j) acc[i][j] = 0.f;

    const int sj = tid & 7;
    const int sr = tid >> 3;

    for (int k0 = 0; k0 < D_; k0 += FBK) {
        __syncthreads();
#pragma unroll
        for (int it = 0; it < 2; ++it) {
            const int m = sr + it * 32;
            const float4 v = *reinterpret_cast<const float4*>(
                &x[(size_t)(block_m0 + m) * D_ + k0 + 4 * sj]);
            Xs[(4 * sj + 0) * XS_STRIDE + m] = v.x;
            Xs[(4 * sj + 1) * XS_STRIDE + m] = v.y;
            Xs[(4 * sj + 2) * XS_STRIDE + m] = v.z;
            Xs[(4 * sj + 3) * XS_STRIDE + m] = v.w;
        }
#pragma unroll
        for (int it = 0; it < 4; ++it) {
            const int n = sr + it * 32;
            const float* wrow = (n < 64) ? &Wg[(size_t)n * D_] : &Wn[(size_t)(n - 64) * D_];
            const float4 v = *reinterpret_cast<const float4*>(&wrow[k0 + 4 * sj]);
            Ws[(4 * sj + 0) * WS_STRIDE + n] = v.x;
            Ws[(4 * sj + 1) * WS_STRIDE + n] = v.y;
            Ws[(4 * sj + 2) * WS_STRIDE + n] = v.z;
            Ws[(4 * sj + 3) * WS_STRIDE + n] = v.w;
        }
        __syncthreads();
#pragma unroll
        for (int k = 0; k < FBK; ++k) {
            const float4 a0 = *reinterpret_cast<const float4*>(&Xs[k * XS_STRIDE + m0]);
            const float4 a1 = *reinterpret_cast<const float4*>(&Xs[k * XS_STRIDE + m0 + 4]);
            const float4 b4 = *reinterpret_cast<const float4*>(&Ws[k * WS_STRIDE + n0]);
            const float am[8] = {a0.x, a0.y, a0.z, a0.w, a1.x, a1.y, a1.z, a1.w};
            const float bb[4] = {b4.x, b4.y, b4.z, b4.w};
#pragma unroll
            for (int i = 0; i < 8; ++i)
#pragma unroll
                for (int j = 0; j < 4; ++j)
                    acc[i][j] = fmaf(am[i], bb[j], acc[i][j]);
        }
    }

    __syncthreads();
    float* Ct = smem;
#pragma unroll
    for (int i = 0; i < 8; ++i)
#pragma unroll
        for (int j = 0; j < 4; ++j)
            Ct[(m0 + i) * FCT_STRIDE + n0 + j] = acc[i][j];
    __syncthreads();

    const int wave = tid >> 6;
    const int lane = tid & 63;
    const float my_bg = bg[lane];
    const float my_bn = bn[lane];
#pragma unroll 1
    for (int tt = 0; tt < 16; ++tt) {
        const int tl = wave * 16 + tt;
        const size_t tg = (size_t)block_m0 + tl;
        const float g = Ct[tl * FCT_STRIDE + lane] + my_bg;
        const float nl = Ct[tl * FCT_STRIDE + 64 + lane] + my_bn;
        const float nz = noise[tg * E_ + lane];
        topk_epilogue(g, nl, nz, lane, tg, out_probs, out_idx);
    }
}

extern "C" void kernel_launch(void* const* d_in, const int* in_sizes, int n_in,
                              void* d_out, int out_size, void* d_ws, size_t ws_size,
                              hipStream_t stream) {
    const float* x = (const float*)d_in[0];
    const float* Wg = (const float*)d_in[1];
    const float* bg = (const float*)d_in[2];
    const float* Wn = (const float*)d_in[3];
    const float* bn = (const float*)d_in[4];
    const float* noise = (const float*)d_in[5];
    float* out_probs = (float*)d_out;
    float* out_idx = out_probs + (size_t)T_ * E_;

    const size_t WSP_BYTES = (size_t)3 * 32768 * 16;  // 1.57 MB
    if (ws_size >= WSP_BYTES) {
        unsigned short* wsp = (unsigned short*)d_ws;
        hipLaunchKernelGGL(w_split_kernel, dim3(128), dim3(256), 0, stream, Wg, Wn, wsp);
        hipLaunchKernelGGL(gemm_topk_kernel, dim3(T_ / BM), dim3(256), 0, stream,
                           x, wsp, bg, bn, noise, out_probs, out_idx);
    } else {
        hipLaunchKernelGGL(noisy_topk_f32_kernel, dim3(T_ / FBM), dim3(256), 0, stream,
                           x, Wg, bg, Wn, bn, noise, out_probs, out_idx);
    }
}

// Round 5
// 78.807 us; speedup vs baseline: 2.2005x; 1.1046x over previous
//
#include <hip/hip_runtime.h>
#include <math.h>
#include <stdint.h>

// NoisyTopKGating: B=4, S=4096, D=2048, E=64, K=2
#define D_ 2048
#define E_ 64
#define T_ 16384

#define BM 64
#define BK 64
#define KTILES (D_ / BK)       // 32
#define ROWB 144               // LDS row stride bytes (72 bf16: 64 data + 8 pad)
#define PLANE_B (BM * ROWB)    // 9216 B per bf16 plane
#define BUF_B (3 * PLANE_B)    // 27648 B per double-buffer half
#define CT_STRIDE 132          // fp32 C tile stride (epilogue)

typedef __attribute__((ext_vector_type(8))) short s8v;   // 8 bf16 (4 VGPR)
typedef __attribute__((ext_vector_type(4))) float f4v;   // MFMA acc

__device__ __forceinline__ unsigned short bf16_rne(float f) {
    union { float f; uint32_t u; } c; c.f = f;
    return (unsigned short)((c.u + 0x7FFFu + ((c.u >> 16) & 1u)) >> 16);
}
__device__ __forceinline__ float bf16_tof(unsigned short b) {
    union { uint32_t u; float f; } c; c.u = ((uint32_t)b) << 16;
    return c.f;
}
// cheap truncation split: f -> hi (bf16-trunc), r = f - hi
__device__ __forceinline__ float split_trunc(float f, short& h) {
    union { float f; uint32_t u; } c; c.f = f;
    h = (short)(c.u >> 16);
    union { uint32_t u; float f; } t; t.u = c.u & 0xFFFF0000u;
    return f - t.f;
}

struct X8 { float4 a, b; };

// ================= per-token noisy top-2 epilogue (shared) ==================
__device__ __forceinline__ void topk_epilogue(float g, float nl, float nz,
                                              int lane, size_t tg,
                                              float* __restrict__ out_probs,
                                              float* __restrict__ out_idx) {
    // softplus(z) = max(z,0) + log1p(exp(-|z|))
    const float sp = fmaxf(nl, 0.f) + log1pf(expf(-fabsf(nl)));
    const float noisy = g + nz * sp;

    float v = noisy;
    int idx = lane;
#pragma unroll
    for (int off = 32; off > 0; off >>= 1) {
        const float ov = __shfl_xor(v, off);
        const int oi = __shfl_xor(idx, off);
        if (ov > v || (ov == v && oi < idx)) { v = ov; idx = oi; }
    }
    const float v1 = v;
    const int i1 = idx;
    v = (lane == i1) ? -INFINITY : noisy;
    idx = lane;
#pragma unroll
    for (int off = 32; off > 0; off >>= 1) {
        const float ov = __shfl_xor(v, off);
        const int oi = __shfl_xor(idx, off);
        if (ov > v || (ov == v && oi < idx)) { v = ov; idx = oi; }
    }
    const float v2 = v;
    const int i2 = idx;

    const float e2 = expf(v2 - v1);
    const float denom = 1.f + e2;
    const float p = (lane == i1) ? (1.f / denom)
                                 : ((lane == i2) ? (e2 / denom) : 0.f);
    out_probs[tg * E_ + lane] = p;
    if (lane == 0) {
        out_idx[tg * 2 + 0] = (float)i1;
        out_idx[tg * 2 + 1] = (float)i2;
    }
}

// ---------------- kernel 1: pre-split W = [Wg;Wn] into 3 bf16 planes --------
// Frag-linear layout: plane p, n-frag f(8), k-step s(64), lane(64) -> 8 bf16.
// b-frag semantics: n = f*16 + (lane&15), k = s*32 + (lane>>4)*8 + i.
__global__ void w_split_kernel(const float* __restrict__ Wg,
                               const float* __restrict__ Wn,
                               unsigned short* __restrict__ wsp) {
    const int idx = blockIdx.x * blockDim.x + threadIdx.x;  // 0..32767
    const int lane = idx & 63;
    const int s = (idx >> 6) & 63;
    const int f = idx >> 12;
    const int n = f * 16 + (lane & 15);
    const int k0 = s * 32 + ((lane >> 4) << 3);
    const float* src = (n < 64) ? &Wg[(size_t)n * D_ + k0]
                                : &Wn[(size_t)(n - 64) * D_ + k0];
    s8v hv, mv, lv;
#pragma unroll
    for (int i = 0; i < 8; ++i) {
        const float f0 = src[i];
        const unsigned short hb = bf16_rne(f0);
        const float r1 = f0 - bf16_tof(hb);
        const unsigned short mb = bf16_rne(r1);
        const unsigned short lb = bf16_rne(r1 - bf16_tof(mb));
        hv[i] = (short)hb; mv[i] = (short)mb; lv[i] = (short)lb;
    }
    s8v* out = (s8v*)wsp;
    const int PLANE_FRAGS = 8 * 64 * 64;  // 32768 frags of 16 B per plane
    out[0 * PLANE_FRAGS + idx] = hv;
    out[1 * PLANE_FRAGS + idx] = mv;
    out[2 * PLANE_FRAGS + idx] = lv;
}

// ---------------- kernel 2: fused split-bf16 MFMA GEMM + noisy top-2 --------
// BM=64, 512 threads = 8 waves (2m x 4n), double-buffered LDS, prefetched x.
__launch_bounds__(512)
__global__ void gemm_topk_kernel(const float* __restrict__ x,
                                 const unsigned short* __restrict__ wsp,
                                 const float* __restrict__ bg,
                                 const float* __restrict__ bn,
                                 const float* __restrict__ noise,
                                 float* __restrict__ out_probs,
                                 float* __restrict__ out_idx) {
    __shared__ __align__(16) char smem[2 * BUF_B];  // 55296 B
    const int tid = threadIdx.x;
    const int lane = tid & 63;
    const int wv = tid >> 6;           // 0..7
    const int wm = wv >> 2;            // 0..1 (m half)
    const int wn = wv & 3;             // 0..3 (n quadrant, 32 cols)
    const int block_m0 = blockIdx.x * BM;

    // staging: thread -> token row sr (0..63), k-chunk sc (8 floats)
    const int sr = tid >> 3;
    const int sc = tid & 7;
    const int wbyte = sr * ROWB + sc * 16;

    // A-frag addressing: row = wm*32 + mi*16 + (lane&15), kb = (lane>>4)*16
    const int arow = lane & 15;
    const int abase = (wm * 32 + arow) * ROWB + (lane >> 4) * 16;

    const s8v* wsv = (const s8v*)wsp;
    const int fb = wn * 2;  // this wave's first n-frag

    f4v acc00{}, acc01{}, acc10{}, acc11{};  // [mi][ni]

    const float* xrow = &x[(size_t)(block_m0 + sr) * D_ + sc * 8];

    // ---- helpers ----
    auto LOADX = [&](int t, X8& r) {
        r.a = *(const float4*)(xrow + t * BK);
        r.b = *(const float4*)(xrow + t * BK + 4);
    };
    auto SPLIT_STORE = [&](const X8& xf, char* bufbase) {
        s8v hv, mv, lv;
        const float xe[8] = {xf.a.x, xf.a.y, xf.a.z, xf.a.w,
                             xf.b.x, xf.b.y, xf.b.z, xf.b.w};
#pragma unroll
        for (int i = 0; i < 8; ++i) {
            short h, m, l;
            float r1 = split_trunc(xe[i], h);
            float r2 = split_trunc(r1, m);
            union { float f; uint32_t u; } c; c.f = r2;
            l = (short)(c.u >> 16);
            hv[i] = h; mv[i] = m; lv[i] = l;
        }
        *(s8v*)(bufbase + 0 * PLANE_B + wbyte) = hv;
        *(s8v*)(bufbase + 1 * PLANE_B + wbyte) = mv;
        *(s8v*)(bufbase + 2 * PLANE_B + wbyte) = lv;
    };
    auto COMPUTE = [&](const char* bufbase, int t) {
#pragma unroll
        for (int ss = 0; ss < 2; ++ss) {
            const size_t bbase = (size_t)(t * 2 + ss) * 64 + lane;
            // B frags (global, L2-resident, coalesced)
            const s8v b0n0 = wsv[(size_t)(0 * 8 + fb + 0) * 4096 + bbase];
            const s8v b0n1 = wsv[(size_t)(0 * 8 + fb + 1) * 4096 + bbase];
            const s8v b1n0 = wsv[(size_t)(1 * 8 + fb + 0) * 4096 + bbase];
            const s8v b1n1 = wsv[(size_t)(1 * 8 + fb + 1) * 4096 + bbase];
            const s8v b2n0 = wsv[(size_t)(2 * 8 + fb + 0) * 4096 + bbase];
            const s8v b2n1 = wsv[(size_t)(2 * 8 + fb + 1) * 4096 + bbase];
            // A frags (LDS)
            const int ab = ss * 64 + abase;
            const s8v a0m0 = *(const s8v*)(bufbase + 0 * PLANE_B + ab);
            const s8v a0m1 = *(const s8v*)(bufbase + 0 * PLANE_B + 16 * ROWB + ab);
            const s8v a1m0 = *(const s8v*)(bufbase + 1 * PLANE_B + ab);
            const s8v a1m1 = *(const s8v*)(bufbase + 1 * PLANE_B + 16 * ROWB + ab);
            const s8v a2m0 = *(const s8v*)(bufbase + 2 * PLANE_B + ab);
            const s8v a2m1 = *(const s8v*)(bufbase + 2 * PLANE_B + 16 * ROWB + ab);

#define MFMA_(A, Bf, C) C = __builtin_amdgcn_mfma_f32_16x16x32_bf16(A, Bf, C, 0, 0, 0)
            MFMA_(a0m0, b0n0, acc00); MFMA_(a0m0, b0n1, acc01);   // hi*hi
            MFMA_(a0m1, b0n0, acc10); MFMA_(a0m1, b0n1, acc11);
            MFMA_(a0m0, b1n0, acc00); MFMA_(a0m0, b1n1, acc01);   // hi*mid
            MFMA_(a0m1, b1n0, acc10); MFMA_(a0m1, b1n1, acc11);
            MFMA_(a1m0, b0n0, acc00); MFMA_(a1m0, b0n1, acc01);   // mid*hi
            MFMA_(a1m1, b0n0, acc10); MFMA_(a1m1, b0n1, acc11);
            MFMA_(a0m0, b2n0, acc00); MFMA_(a0m0, b2n1, acc01);   // hi*lo
            MFMA_(a0m1, b2n0, acc10); MFMA_(a0m1, b2n1, acc11);
            MFMA_(a1m0, b1n0, acc00); MFMA_(a1m0, b1n1, acc01);   // mid*mid
            MFMA_(a1m1, b1n0, acc10); MFMA_(a1m1, b1n1, acc11);
            MFMA_(a2m0, b0n0, acc00); MFMA_(a2m0, b0n1, acc01);   // lo*hi
            MFMA_(a2m1, b0n0, acc10); MFMA_(a2m1, b0n1, acc11);
#undef MFMA_
        }
    };

    // ---- software-pipelined main loop (1 barrier / K-tile) ----
    X8 xfA, xfB;
    LOADX(0, xfA);
    LOADX(1, xfB);
    SPLIT_STORE(xfA, smem);            // buf0 <- tile 0
    __syncthreads();

#pragma unroll 1
    for (int tt = 0; tt < KTILES; tt += 2) {
        // even: compute tile tt from buf0; stage tile tt+1 into buf1
        {
            const int tn = (tt + 2 < KTILES) ? tt + 2 : KTILES - 1;
            LOADX(tn, xfA);                      // prefetch (xfA was consumed)
            COMPUTE(smem, tt);
            SPLIT_STORE(xfB, smem + BUF_B);      // buf1 <- tile tt+1
            __syncthreads();
        }
        // odd: compute tile tt+1 from buf1; stage tile tt+2 into buf0
        {
            const int tn = (tt + 3 < KTILES) ? tt + 3 : KTILES - 1;
            LOADX(tn, xfB);
            COMPUTE(smem + BUF_B, tt + 1);
            SPLIT_STORE(xfA, smem);              // buf0 <- tile tt+2
            __syncthreads();
        }
    }

    // ---- epilogue: C tile to LDS (fp32), then per-token noisy top-2 ----
    float* Ct = (float*)smem;  // [64][CT_STRIDE] = 33792 B
    {
        const int ko4 = (lane >> 4) * 4;
        const f4v* accs[2][2] = {{&acc00, &acc01}, {&acc10, &acc11}};
#pragma unroll
        for (int mi = 0; mi < 2; ++mi)
#pragma unroll
            for (int ni = 0; ni < 2; ++ni) {
                const int col = wn * 32 + ni * 16 + arow;
#pragma unroll
                for (int r = 0; r < 4; ++r) {
                    const int row = wm * 32 + mi * 16 + ko4 + r;
                    Ct[row * CT_STRIDE + col] = (*accs[mi][ni])[r];
                }
            }
    }
    __syncthreads();

    const float my_bg = bg[lane];
    const float my_bn = bn[lane];
#pragma unroll 1
    for (int tt = 0; tt < 8; ++tt) {
        const int tl = wv * 8 + tt;
        const size_t tg = (size_t)block_m0 + tl;
        const float g = Ct[tl * CT_STRIDE + lane] + my_bg;
        const float nl = Ct[tl * CT_STRIDE + 64 + lane] + my_bn;
        const float nz = noise[tg * E_ + lane];
        topk_epilogue(g, nl, nz, lane, tg, out_probs, out_idx);
    }
}

// ---------------- fallback: pure-f32 fused kernel (no ws) -------------------
#define FBM 64
#define FBK 32
#define XS_STRIDE 68
#define WS_STRIDE 132
#define FCT_STRIDE 132

__launch_bounds__(256)
__global__ void noisy_topk_f32_kernel(const float* __restrict__ x,
                                      const float* __restrict__ Wg,
                                      const float* __restrict__ bg,
                                      const float* __restrict__ Wn,
                                      const float* __restrict__ bn,
                                      const float* __restrict__ noise,
                                      float* __restrict__ out_probs,
                                      float* __restrict__ out_idx) {
    __shared__ float smem[FBM * FCT_STRIDE];
    float* Xs = smem;
    float* Ws = smem + FBK * XS_STRIDE;

    const int tid = threadIdx.x;
    const int block_m0 = blockIdx.x * FBM;
    const int n0 = (tid & 31) * 4;
    const int m0 = (tid >> 5) * 8;

    float acc[8][4];
#pragma unroll
    for (int i = 0; i < 8; ++i)
#pragma unroll
        for (int j = 0; j < 4; ++j) acc[i][j] = 0.f;

    const int sj = tid & 7;
    const int sr = tid >> 3;

    for (int k0 = 0; k0 < D_; k0 += FBK) {
        __syncthreads();
#pragma unroll
        for (int it = 0; it < 2; ++it) {
            const int m = sr + it * 32;
            const float4 v = *reinterpret_cast<const float4*>(
                &x[(size_t)(block_m0 + m) * D_ + k0 + 4 * sj]);
            Xs[(4 * sj + 0) * XS_STRIDE + m] = v.x;
            Xs[(4 * sj + 1) * XS_STRIDE + m] = v.y;
            Xs[(4 * sj + 2) * XS_STRIDE + m] = v.z;
            Xs[(4 * sj + 3) * XS_STRIDE + m] = v.w;
        }
#pragma unroll
        for (int it = 0; it < 4; ++it) {
            const int n = sr + it * 32;
            const float* wrow = (n < 64) ? &Wg[(size_t)n * D_] : &Wn[(size_t)(n - 64) * D_];
            const float4 v = *reinterpret_cast<const float4*>(&wrow[k0 + 4 * sj]);
            Ws[(4 * sj + 0) * WS_STRIDE + n] = v.x;
            Ws[(4 * sj + 1) * WS_STRIDE + n] = v.y;
            Ws[(4 * sj + 2) * WS_STRIDE + n] = v.z;
            Ws[(4 * sj + 3) * WS_STRIDE + n] = v.w;
        }
        __syncthreads();
#pragma unroll
        for (int k = 0; k < FBK; ++k) {
            const float4 a0 = *reinterpret_cast<const float4*>(&Xs[k * XS_STRIDE + m0]);
            const float4 a1 = *reinterpret_cast<const float4*>(&Xs[k * XS_STRIDE + m0 + 4]);
            const float4 b4 = *reinterpret_cast<const float4*>(&Ws[k * WS_STRIDE + n0]);
            const float am[8] = {a0.x, a0.y, a0.z, a0.w, a1.x, a1.y, a1.z, a1.w};
            const float bb[4] = {b4.x, b4.y, b4.z, b4.w};
#pragma unroll
            for (int i = 0; i < 8; ++i)
#pragma unroll
                for (int j = 0; j < 4; ++j)
                    acc[i][j] = fmaf(am[i], bb[j], acc[i][j]);
        }
    }

    __syncthreads();
    float* Ct = smem;
#pragma unroll
    for (int i = 0; i < 8; ++i)
#pragma unroll
        for (int j = 0; j < 4; ++j)
            Ct[(m0 + i) * FCT_STRIDE + n0 + j] = acc[i][j];
    __syncthreads();

    const int wave = tid >> 6;
    const int lane = tid & 63;
    const float my_bg = bg[lane];
    const float my_bn = bn[lane];
#pragma unroll 1
    for (int tt = 0; tt < 16; ++tt) {
        const int tl = wave * 16 + tt;
        const size_t tg = (size_t)block_m0 + tl;
        const float g = Ct[tl * FCT_STRIDE + lane] + my_bg;
        const float nl = Ct[tl * FCT_STRIDE + 64 + lane] + my_bn;
        const float nz = noise[tg * E_ + lane];
        topk_epilogue(g, nl, nz, lane, tg, out_probs, out_idx);
    }
}

extern "C" void kernel_launch(void* const* d_in, const int* in_sizes, int n_in,
                              void* d_out, int out_size, void* d_ws, size_t ws_size,
                              hipStream_t stream) {
    const float* x = (const float*)d_in[0];
    const float* Wg = (const float*)d_in[1];
    const float* bg = (const float*)d_in[2];
    const float* Wn = (const float*)d_in[3];
    const float* bn = (const float*)d_in[4];
    const float* noise = (const float*)d_in[5];
    float* out_probs = (float*)d_out;
    float* out_idx = out_probs + (size_t)T_ * E_;

    const size_t WSP_BYTES = (size_t)3 * 32768 * 16;  // 1.57 MB
    if (ws_size >= WSP_BYTES) {
        unsigned short* wsp = (unsigned short*)d_ws;
        hipLaunchKernelGGL(w_split_kernel, dim3(128), dim3(256), 0, stream, Wg, Wn, wsp);
        hipLaunchKernelGGL(gemm_topk_kernel, dim3(T_ / BM), dim3(512), 0, stream,
                           x, wsp, bg, bn, noise, out_probs, out_idx);
    } else {
        hipLaunchKernelGGL(noisy_topk_f32_kernel, dim3(T_ / FBM), dim3(256), 0, stream,
                           x, Wg, bg, Wn, bn, noise, out_probs, out_idx);
    }
}

// Round 7
// 73.687 us; speedup vs baseline: 2.3534x; 1.0695x over previous
//
#include <hip/hip_runtime.h>
#include <math.h>
#include <stdint.h>

// NoisyTopKGating: B=4, S=4096, D=2048, E=64, K=2
#define D_ 2048
#define E_ 64
#define T_ 16384

#define BM 64
#define BK 64
#define KTILES (D_ / BK)       // 32
#define ROWB 144               // LDS row stride bytes (72 bf16: 64 data + 8 pad)
#define PLANE_B (BM * ROWB)    // 9216 B per bf16 plane
#define BUF_B (3 * PLANE_B)    // 27648 B per double-buffer half
#define CT_STRIDE 132          // fp32 C tile stride (epilogue)

typedef __attribute__((ext_vector_type(8))) short s8v;   // 8 bf16 (4 VGPR)
typedef __attribute__((ext_vector_type(4))) float f4v;   // MFMA acc

__device__ __forceinline__ unsigned short bf16_rne(float f) {
    union { float f; uint32_t u; } c; c.f = f;
    return (unsigned short)((c.u + 0x7FFFu + ((c.u >> 16) & 1u)) >> 16);
}
__device__ __forceinline__ float bf16_tof(unsigned short b) {
    union { uint32_t u; float f; } c; c.u = ((uint32_t)b) << 16;
    return c.f;
}
// cheap truncation split: f -> hi (bf16-trunc), r = f - hi
__device__ __forceinline__ float split_trunc(float f, short& h) {
    union { float f; uint32_t u; } c; c.f = f;
    h = (short)(c.u >> 16);
    union { uint32_t u; float f; } t; t.u = c.u & 0xFFFF0000u;
    return f - t.f;
}

struct X8 { float4 a, b; };

// ================= per-token noisy top-2 epilogue (shared) ==================
__device__ __forceinline__ void topk_epilogue(float g, float nl, float nz,
                                              int lane, size_t tg,
                                              float* __restrict__ out_probs,
                                              float* __restrict__ out_idx) {
    // softplus(z) = max(z,0) + log1p(exp(-|z|))
    const float sp = fmaxf(nl, 0.f) + log1pf(expf(-fabsf(nl)));
    const float noisy = g + nz * sp;

    float v = noisy;
    int idx = lane;
#pragma unroll
    for (int off = 32; off > 0; off >>= 1) {
        const float ov = __shfl_xor(v, off);
        const int oi = __shfl_xor(idx, off);
        if (ov > v || (ov == v && oi < idx)) { v = ov; idx = oi; }
    }
    const float v1 = v;
    const int i1 = idx;
    v = (lane == i1) ? -INFINITY : noisy;
    idx = lane;
#pragma unroll
    for (int off = 32; off > 0; off >>= 1) {
        const float ov = __shfl_xor(v, off);
        const int oi = __shfl_xor(idx, off);
        if (ov > v || (ov == v && oi < idx)) { v = ov; idx = oi; }
    }
    const float v2 = v;
    const int i2 = idx;

    const float e2 = expf(v2 - v1);
    const float denom = 1.f + e2;
    const float p = (lane == i1) ? (1.f / denom)
                                 : ((lane == i2) ? (e2 / denom) : 0.f);
    out_probs[tg * E_ + lane] = p;
    if (lane == 0) {
        out_idx[tg * 2 + 0] = (float)i1;
        out_idx[tg * 2 + 1] = (float)i2;
    }
}

// ---------------- kernel 1: pre-split W = [Wg;Wn] into 3 bf16 planes --------
// Frag-linear layout: plane p, n-frag f(8), k-step s(64), lane(64) -> 8 bf16.
// b-frag semantics: n = f*16 + (lane&15), k = s*32 + (lane>>4)*8 + i.
__global__ void w_split_kernel(const float* __restrict__ Wg,
                               const float* __restrict__ Wn,
                               unsigned short* __restrict__ wsp) {
    const int idx = blockIdx.x * blockDim.x + threadIdx.x;  // 0..32767
    const int lane = idx & 63;
    const int s = (idx >> 6) & 63;
    const int f = idx >> 12;
    const int n = f * 16 + (lane & 15);
    const int k0 = s * 32 + ((lane >> 4) << 3);
    const float* src = (n < 64) ? &Wg[(size_t)n * D_ + k0]
                                : &Wn[(size_t)(n - 64) * D_ + k0];
    s8v hv, mv, lv;
#pragma unroll
    for (int i = 0; i < 8; ++i) {
        const float f0 = src[i];
        const unsigned short hb = bf16_rne(f0);
        const float r1 = f0 - bf16_tof(hb);
        const unsigned short mb = bf16_rne(r1);
        const unsigned short lb = bf16_rne(r1 - bf16_tof(mb));
        hv[i] = (short)hb; mv[i] = (short)mb; lv[i] = (short)lb;
    }
    s8v* out = (s8v*)wsp;
    const int PLANE_FRAGS = 8 * 64 * 64;  // 32768 frags of 16 B per plane
    out[0 * PLANE_FRAGS + idx] = hv;
    out[1 * PLANE_FRAGS + idx] = mv;
    out[2 * PLANE_FRAGS + idx] = lv;
}

// ---------------- kernel 2: fused split-bf16 MFMA GEMM + noisy top-2 --------
// BM=64, 512 threads = 8 waves (2m x 4n), double-buffered LDS,
// register-prefetched B (1 K-tile ahead) + prefetched x.
__launch_bounds__(512, 2)
__global__ void gemm_topk_kernel(const float* __restrict__ x,
                                 const unsigned short* __restrict__ wsp,
                                 const float* __restrict__ bg,
                                 const float* __restrict__ bn,
                                 const float* __restrict__ noise,
                                 float* __restrict__ out_probs,
                                 float* __restrict__ out_idx) {
    __shared__ __align__(16) char smem[2 * BUF_B];  // 55296 B
    const int tid = threadIdx.x;
    const int lane = tid & 63;
    const int wv = tid >> 6;           // 0..7
    const int wm = wv >> 2;            // 0..1 (m half)
    const int wn = wv & 3;             // 0..3 (n quadrant, 32 cols)
    const int block_m0 = blockIdx.x * BM;

    // staging: thread -> token row sr (0..63), k-chunk sc (8 floats)
    const int sr = tid >> 3;
    const int sc = tid & 7;
    const int wbyte = sr * ROWB + sc * 16;

    // A-frag addressing: row = wm*32 + mi*16 + (lane&15), kb = (lane>>4)*16
    const int arow = lane & 15;
    const int abase = (wm * 32 + arow) * ROWB + (lane >> 4) * 16;

    const s8v* wsv = (const s8v*)wsp;
    const int fb = wn * 2;  // this wave's first n-frag

    f4v acc00{}, acc01{}, acc10{}, acc11{};  // [mi][ni]

    const float* xrow = &x[(size_t)(block_m0 + sr) * D_ + sc * 8];

    // ---- helpers ----
    auto LOADX = [&](int t, X8& r) {
        r.a = *(const float4*)(xrow + t * BK);
        r.b = *(const float4*)(xrow + t * BK + 4);
    };
    // B-frag register prefetch: 12 s8v per K-tile, idx = ss*6 + p*2 + f
    auto LOADB = [&](int t, s8v* Bf) {
#pragma unroll
        for (int ss = 0; ss < 2; ++ss) {
            const size_t bbase = (size_t)(t * 2 + ss) * 64 + lane;
#pragma unroll
            for (int p = 0; p < 3; ++p)
#pragma unroll
                for (int f = 0; f < 2; ++f)
                    Bf[ss * 6 + p * 2 + f] = wsv[(size_t)(p * 8 + fb + f) * 4096 + bbase];
        }
    };
    auto SPLIT_STORE = [&](const X8& xf, char* bufbase) {
        s8v hv, mv, lv;
        const float xe[8] = {xf.a.x, xf.a.y, xf.a.z, xf.a.w,
                             xf.b.x, xf.b.y, xf.b.z, xf.b.w};
#pragma unroll
        for (int i = 0; i < 8; ++i) {
            short h, m, l;
            float r1 = split_trunc(xe[i], h);
            float r2 = split_trunc(r1, m);
            union { float f; uint32_t u; } c; c.f = r2;
            l = (short)(c.u >> 16);
            hv[i] = h; mv[i] = m; lv[i] = l;
        }
        *(s8v*)(bufbase + 0 * PLANE_B + wbyte) = hv;
        *(s8v*)(bufbase + 1 * PLANE_B + wbyte) = mv;
        *(s8v*)(bufbase + 2 * PLANE_B + wbyte) = lv;
    };
    // A idx = ss*6 + p*2 + mi (all compile-time after unroll)
    auto COMPUTE = [&](const char* bufbase, const s8v* Bf) {
        s8v A[12];
#pragma unroll
        for (int ss = 0; ss < 2; ++ss)
#pragma unroll
            for (int p = 0; p < 3; ++p)
#pragma unroll
                for (int mi = 0; mi < 2; ++mi)
                    A[ss * 6 + p * 2 + mi] = *(const s8v*)(
                        bufbase + p * PLANE_B + mi * 16 * ROWB + ss * 64 + abase);
#pragma unroll
        for (int ss = 0; ss < 2; ++ss) {
            const s8v* As = A + ss * 6;
            const s8v* Bs = Bf + ss * 6;
#define MFMA_(Ai, Bi, C) C = __builtin_amdgcn_mfma_f32_16x16x32_bf16(As[Ai], Bs[Bi], C, 0, 0, 0)
            MFMA_(0, 0, acc00); MFMA_(0, 1, acc01); MFMA_(1, 0, acc10); MFMA_(1, 1, acc11); // hi*hi
            MFMA_(0, 2, acc00); MFMA_(0, 3, acc01); MFMA_(1, 2, acc10); MFMA_(1, 3, acc11); // hi*mid
            MFMA_(2, 0, acc00); MFMA_(2, 1, acc01); MFMA_(3, 0, acc10); MFMA_(3, 1, acc11); // mid*hi
            MFMA_(0, 4, acc00); MFMA_(0, 5, acc01); MFMA_(1, 4, acc10); MFMA_(1, 5, acc11); // hi*lo
            MFMA_(2, 2, acc00); MFMA_(2, 3, acc01); MFMA_(3, 2, acc10); MFMA_(3, 3, acc11); // mid*mid
            MFMA_(4, 0, acc00); MFMA_(4, 1, acc01); MFMA_(5, 0, acc10); MFMA_(5, 1, acc11); // lo*hi
#undef MFMA_
        }
    };

    // ---- software-pipelined main loop (1 barrier / K-tile) ----
    // In flight at COMPUTE(t): B(t) in regs (loaded tile t-1), x(t+1) in regs,
    // next B(t+1) issued right after the barrier (latency hidden under t).
    X8 xfA, xfB;
    s8v BA[12], BB[12];
    LOADX(0, xfA);
    LOADX(1, xfB);
    LOADB(0, BA);
    SPLIT_STORE(xfA, smem);            // buf0 <- tile 0
    __syncthreads();

#pragma unroll 1
    for (int tt = 0; tt < KTILES; tt += 2) {
        // even: compute tile tt from buf0 (B in BA); stage tile tt+1 -> buf1
        {
            LOADB(tt + 1, BB);                   // prefetch next B into regs
            const int tn = (tt + 2 < KTILES) ? tt + 2 : KTILES - 1;
            LOADX(tn, xfA);                      // prefetch x (xfA consumed)
            COMPUTE(smem, BA);
            SPLIT_STORE(xfB, smem + BUF_B);      // buf1 <- tile tt+1
            __syncthreads();
        }
        // odd: compute tile tt+1 from buf1 (B in BB); stage tile tt+2 -> buf0
        {
            const int tb = (tt + 2 < KTILES) ? tt + 2 : KTILES - 1;
            LOADB(tb, BA);
            const int tn = (tt + 3 < KTILES) ? tt + 3 : KTILES - 1;
            LOADX(tn, xfB);
            COMPUTE(smem + BUF_B, BB);
            SPLIT_STORE(xfA, smem);              // buf0 <- tile tt+2
            __syncthreads();
        }
    }

    // ---- epilogue: C tile to LDS (fp32), then per-token noisy top-2 ----
    float* Ct = (float*)smem;  // [64][CT_STRIDE] = 33792 B
    {
        const int ko4 = (lane >> 4) * 4;
        const f4v* accs[2][2] = {{&acc00, &acc01}, {&acc10, &acc11}};
#pragma unroll
        for (int mi = 0; mi < 2; ++mi)
#pragma unroll
            for (int ni = 0; ni < 2; ++ni) {
                const int col = wn * 32 + ni * 16 + arow;
#pragma unroll
                for (int r = 0; r < 4; ++r) {
                    const int row = wm * 32 + mi * 16 + ko4 + r;
                    Ct[row * CT_STRIDE + col] = (*accs[mi][ni])[r];
                }
            }
    }
    __syncthreads();

    const float my_bg = bg[lane];
    const float my_bn = bn[lane];
#pragma unroll 1
    for (int tt = 0; tt < 8; ++tt) {
        const int tl = wv * 8 + tt;
        const size_t tg = (size_t)block_m0 + tl;
        const float g = Ct[tl * CT_STRIDE + lane] + my_bg;
        const float nl = Ct[tl * CT_STRIDE + 64 + lane] + my_bn;
        const float nz = noise[tg * E_ + lane];
        topk_epilogue(g, nl, nz, lane, tg, out_probs, out_idx);
    }
}

// ---------------- fallback: pure-f32 fused kernel (no ws) -------------------
#define FBM 64
#define FBK 32
#define XS_STRIDE 68
#define WS_STRIDE 132
#define FCT_STRIDE 132

__launch_bounds__(256)
__global__ void noisy_topk_f32_kernel(const float* __restrict__ x,
                                      const float* __restrict__ Wg,
                                      const float* __restrict__ bg,
                                      const float* __restrict__ Wn,
                                      const float* __restrict__ bn,
                                      const float* __restrict__ noise,
                                      float* __restrict__ out_probs,
                                      float* __restrict__ out_idx) {
    __shared__ float smem[FBM * FCT_STRIDE];
    float* Xs = smem;
    float* Ws = smem + FBK * XS_STRIDE;

    const int tid = threadIdx.x;
    const int block_m0 = blockIdx.x * FBM;
    const int n0 = (tid & 31) * 4;
    const int m0 = (tid >> 5) * 8;

    float acc[8][4];
#pragma unroll
    for (int i = 0; i < 8; ++i)
#pragma unroll
        for (int j = 0; j < 4; ++j) acc[i][j] = 0.f;

    const int sj = tid & 7;
    const int sr = tid >> 3;

    for (int k0 = 0; k0 < D_; k0 += FBK) {
        __syncthreads();
#pragma unroll
        for (int it = 0; it < 2; ++it) {
            const int m = sr + it * 32;
            const float4 v = *reinterpret_cast<const float4*>(
                &x[(size_t)(block_m0 + m) * D_ + k0 + 4 * sj]);
            Xs[(4 * sj + 0) * XS_STRIDE + m] = v.x;
            Xs[(4 * sj + 1) * XS_STRIDE + m] = v.y;
            Xs[(4 * sj + 2) * XS_STRIDE + m] = v.z;
            Xs[(4 * sj + 3) * XS_STRIDE + m] = v.w;
        }
#pragma unroll
        for (int it = 0; it < 4; ++it) {
            const int n = sr + it * 32;
            const float* wrow = (n < 64) ? &Wg[(size_t)n * D_] : &Wn[(size_t)(n - 64) * D_];
            const float4 v = *reinterpret_cast<const float4*>(&wrow[k0 + 4 * sj]);
            Ws[(4 * sj + 0) * WS_STRIDE + n] = v.x;
            Ws[(4 * sj + 1) * WS_STRIDE + n] = v.y;
            Ws[(4 * sj + 2) * WS_STRIDE + n] = v.z;
            Ws[(4 * sj + 3) * WS_STRIDE + n] = v.w;
        }
        __syncthreads();
#pragma unroll
        for (int k = 0; k < FBK; ++k) {
            const float4 a0 = *reinterpret_cast<const float4*>(&Xs[k * XS_STRIDE + m0]);
            const float4 a1 = *reinterpret_cast<const float4*>(&Xs[k * XS_STRIDE + m0 + 4]);
            const float4 b4 = *reinterpret_cast<const float4*>(&Ws[k * WS_STRIDE + n0]);
            const float am[8] = {a0.x, a0.y, a0.z, a0.w, a1.x, a1.y, a1.z, a1.w};
            const float bb[4] = {b4.x, b4.y, b4.z, b4.w};
#pragma unroll
            for (int i = 0; i < 8; ++i)
#pragma unroll
                for (int j = 0; j < 4; ++j)
                    acc[i][j] = fmaf(am[i], bb[j], acc[i][j]);
        }
    }

    __syncthreads();
    float* Ct = smem;
#pragma unroll
    for (int i = 0; i < 8; ++i)
#pragma unroll
        for (int j = 0; j < 4; ++j)
            Ct[(m0 + i) * FCT_STRIDE + n0 + j] = acc[i][j];
    __syncthreads();

    const int wave = tid >> 6;
    const int lane = tid & 63;
    const float my_bg = bg[lane];
    const float my_bn = bn[lane];
#pragma unroll 1
    for (int tt = 0; tt < 16; ++tt) {
        const int tl = wave * 16 + tt;
        const size_t tg = (size_t)block_m0 + tl;
        const float g = Ct[tl * FCT_STRIDE + lane] + my_bg;
        const float nl = Ct[tl * FCT_STRIDE + 64 + lane] + my_bn;
        const float nz = noise[tg * E_ + lane];
        topk_epilogue(g, nl, nz, lane, tg, out_probs, out_idx);
    }
}

extern "C" void kernel_launch(void* const* d_in, const int* in_sizes, int n_in,
                              void* d_out, int out_size, void* d_ws, size_t ws_size,
                              hipStream_t stream) {
    const float* x = (const float*)d_in[0];
    const float* Wg = (const float*)d_in[1];
    const float* bg = (const float*)d_in[2];
    const float* Wn = (const float*)d_in[3];
    const float* bn = (const float*)d_in[4];
    const float* noise = (const float*)d_in[5];
    float* out_probs = (float*)d_out;
    float* out_idx = out_probs + (size_t)T_ * E_;

    const size_t WSP_BYTES = (size_t)3 * 32768 * 16;  // 1.57 MB
    if (ws_size >= WSP_BYTES) {
        unsigned short* wsp = (unsigned short*)d_ws;
        hipLaunchKernelGGL(w_split_kernel, dim3(128), dim3(256), 0, stream, Wg, Wn, wsp);
        hipLaunchKernelGGL(gemm_topk_kernel, dim3(T_ / BM), dim3(512), 0, stream,
                           x, wsp, bg, bn, noise, out_probs, out_idx);
    } else {
        hipLaunchKernelGGL(noisy_topk_f32_kernel, dim3(T_ / FBM), dim3(256), 0, stream,
                           x, Wg, bg, Wn, bn, noise, out_probs, out_idx);
    }
}